// Round 11
// baseline (181.058 us; speedup 1.0000x reference)
//
#include <hip/hip_runtime.h>

typedef _Float16 h2 __attribute__((ext_vector_type(2)));
typedef _Float16 h8 __attribute__((ext_vector_type(8)));

#define BB 256
#define II 1152
#define QQ 8
#define JJ 10
#define PP 16

#define BT 16            // b per block (256 threads = 16 b-groups x 16 p-lanes)
#define IT 8             // i per block
#define NBT (BB / BT)    // 16
#define NIT (II / IT)    // 144
#define XRH 72           // halfs per staged-x b-row (64 + 8 pad)
#define WTILE (IT * PP * QQ)     // 1024 halfs per j in the LDS W-tile

#define NW (JJ * II * PP * QQ)   // 1474560
#define NX (BB * II * QQ)        // 2359296
#define NS (BB * JJ * PP)        // 40960
#define LOG2E 1.4426950408889634f

// ---------------------------------------------------------------------------
// 16-lane row sum via DPP (VALU pipe only).
// ---------------------------------------------------------------------------
template <int CTRL>
__device__ __forceinline__ float dpp_add(float v) {
    int s = __builtin_bit_cast(int, v);
    int t = __builtin_amdgcn_update_dpp(0, s, CTRL, 0xF, 0xF, true);
    return v + __builtin_bit_cast(float, t);
}
__device__ __forceinline__ float row_sum16(float v) {
    v = dpp_add<0xB1>(v);   // xor1
    v = dpp_add<0x4E>(v);   // xor2
    v = dpp_add<0x124>(v);  // row_ror:4
    v = dpp_add<0x128>(v);  // row_ror:8
    return v;
}

// 8-element f16 dot with fp32 accumulate: 4 x v_dot2_f32_f16.
__device__ __forceinline__ float dot8(h8 w, h8 x) {
    h2 w0 = __builtin_shufflevector(w, w, 0, 1), w1 = __builtin_shufflevector(w, w, 2, 3);
    h2 w2 = __builtin_shufflevector(w, w, 4, 5), w3 = __builtin_shufflevector(w, w, 6, 7);
    h2 x0 = __builtin_shufflevector(x, x, 0, 1), x1 = __builtin_shufflevector(x, x, 2, 3);
    h2 x2 = __builtin_shufflevector(x, x, 4, 5), x3 = __builtin_shufflevector(x, x, 6, 7);
    float acc = __builtin_amdgcn_fdot2(w0, x0, 0.0f, false);
    acc = __builtin_amdgcn_fdot2(w1, x1, acc, false);
    acc = __builtin_amdgcn_fdot2(w2, x2, acc, false);
    acc = __builtin_amdgcn_fdot2(w3, x3, acc, false);
    return acc;
}

// ---------------------------------------------------------------------------
// prep: W,X fp32 -> f16. (No S zeroing: partial buffer P is fully overwritten.)
// ---------------------------------------------------------------------------
__global__ __launch_bounds__(256) void prep_kernel(
    const float* __restrict__ X, const float* __restrict__ W,
    _Float16* __restrict__ Xh, _Float16* __restrict__ Wh)
{
    const int g = blockIdx.x * 256 + threadIdx.x;
    const int stride = gridDim.x * 256;
    typedef _Float16 h4 __attribute__((ext_vector_type(4)));
    for (int k = g; k < NW / 4; k += stride) {
        const float4 f = ((const float4*)W)[k];
        h4 o = { (_Float16)f.x, (_Float16)f.y, (_Float16)f.z, (_Float16)f.w };
        ((h4*)Wh)[k] = o;
    }
    for (int k = g; k < NX / 4; k += stride) {
        const float4 f = ((const float4*)X)[k];
        h4 o = { (_Float16)f.x, (_Float16)f.y, (_Float16)f.z, (_Float16)f.w };
        ((h4*)Xh)[k] = o;
    }
}

// ---------------------------------------------------------------------------
// Fused routing pass, LDS-fed, NO ATOMICS: each block writes its partial
// s-tile to a private slice P[it][b][j][p] (plain coalesced stores). The
// 144-way cross-it reduction moves to red_kernel (was 144 serialized atomic
// RMWs per S-slot — the R10 hidden floor).
// vv (= v * log2e) is precomputed by red_kernel; pass reads it directly.
// ---------------------------------------------------------------------------
template <int R>
__global__ __launch_bounds__(256, 4) void pass_kernel(
    const _Float16* __restrict__ Xh,  // [B][I][Q] f16
    const _Float16* __restrict__ Wh,  // [J][I][P][Q] f16
    const float* __restrict__ VV,     // [B][J][P] v*log2e (null at R==0)
    float* __restrict__ P)            // [NIT][B][J][P] partial sums
{
    __shared__ _Float16 ws[JJ * WTILE];  // 20 KB
    __shared__ _Float16 xs[BT * XRH];    // 2.25 KB

    const int bt = blockIdx.x & (NBT - 1);
    const int it = blockIdx.x >> 4;
    const int b0 = bt * BT;
    const int i0 = it * IT;
    const int tid = threadIdx.x;

    // ---- stage W tile: 1280 h8 chunks, 5 per thread (coalesced 16B/lane)
    {
        const size_t jstride = (size_t)II * PP * QQ;
        const _Float16* wsrc = Wh + (size_t)i0 * PP * QQ;
#pragma unroll
        for (int k = 0; k < 5; ++k) {
            const int c = tid + k * 256;   // 0..1279
            const int j = c >> 7;          // 128 h8 chunks per j
            const int r = c & 127;
            *(h8*)(ws + j * WTILE + r * 8) = *(const h8*)(wsrc + j * jstride + r * 8);
        }
        if (tid < 128) {
            const int xb = tid >> 3;
            const int xr = tid & 7;
            *(h8*)(xs + xb * XRH + xr * 8) =
                *(const h8*)(Xh + ((size_t)(b0 + xb) * II + i0) * QQ + xr * 8);
        }
    }
    __syncthreads();

    const int b_l = tid >> 4;
    const int p   = tid & 15;
    const int b   = b0 + b_l;

    float vv[JJ];
    if (R > 0) {
#pragma unroll
        for (int j = 0; j < JJ; ++j)
            vv[j] = VV[((size_t)b * JJ + j) * PP + p];
    }

    float sacc[JJ];
#pragma unroll
    for (int j = 0; j < JJ; ++j) sacc[j] = 0.0f;

#pragma unroll
    for (int i = 0; i < IT; ++i) {
        const h8 x8 = *(const h8*)(xs + b_l * XRH + i * QQ);

        float h[JJ];
#pragma unroll
        for (int j = 0; j < JJ; ++j)
            h[j] = dot8(*(const h8*)(ws + j * WTILE + (i * PP + p) * QQ), x8);

        if (R == 0) {
#pragma unroll
            for (int j = 0; j < JJ; ++j) sacc[j] += h[j];
        } else {
            float e[JJ];
#pragma unroll
            for (int j = 0; j < JJ; ++j) {
                const float bj = row_sum16(vv[j] * h[j]);
                e[j] = exp2f(bj);
            }
            float s01 = e[0] + e[1], s23 = e[2] + e[3], s45 = e[4] + e[5],
                  s67 = e[6] + e[7], s89 = e[8] + e[9];
            float t0 = s01 + s23, t1 = s45 + s67;
            const float sum = (t0 + t1) + s89;
            const float inv = __builtin_amdgcn_rcpf(sum);
#pragma unroll
            for (int j = 0; j < JJ; ++j) sacc[j] += (e[j] * inv) * h[j];
        }
    }

    // plain stores to the block's private slice (coalesced 64B segments)
    float* dst = P + ((size_t)it * BB + b) * (JJ * PP) + p;
#pragma unroll
    for (int j = 0; j < JJ; ++j)
        dst[j * PP] = (R == 0) ? 0.1f * sacc[j] : sacc[j];
}

// ---------------------------------------------------------------------------
// red_kernel: S[idx] = sum_it P[it][idx]; v = squash(S) per (b,j) row of 16
// (p == lane&15, so the norm is a DPP row_sum16).
//  MODE 0: V0raw = v;        VV1 = v*log2e        (after pass0)
//  MODE 1: VV2 = (v+V0raw)*log2e                  (after pass1)
//  MODE 2: out = v                                (final)
// ---------------------------------------------------------------------------
template <int MODE>
__global__ __launch_bounds__(256) void red_kernel(
    const float* __restrict__ P,      // [NIT][NS]
    float* __restrict__ V0raw,
    float* __restrict__ VVout,        // VV1 (MODE0) / VV2 (MODE1) / out (MODE2)
    float* __restrict__ VV1_unused)
{
    const int idx = blockIdx.x * 256 + threadIdx.x;   // 0..NS-1
    // 4 independent accumulator chains over the 144 slices
    float a0 = 0.f, a1 = 0.f, a2 = 0.f, a3 = 0.f;
#pragma unroll 4
    for (int it = 0; it < NIT; it += 4) {
        a0 += P[(size_t)(it + 0) * NS + idx];
        a1 += P[(size_t)(it + 1) * NS + idx];
        a2 += P[(size_t)(it + 2) * NS + idx];
        a3 += P[(size_t)(it + 3) * NS + idx];
    }
    const float s = (a0 + a1) + (a2 + a3);

    const float n2 = row_sum16(s * s);
    const float scale = n2 / (1.0f + n2) / sqrtf(n2 + 1e-7f);
    const float v = s * scale;

    if (MODE == 0) {
        V0raw[idx] = v;
        VVout[idx] = v * LOG2E;
    } else if (MODE == 1) {
        VVout[idx] = (v + V0raw[idx]) * LOG2E;
    } else {
        VVout[idx] = v;
    }
}

extern "C" void kernel_launch(void* const* d_in, const int* in_sizes, int n_in,
                              void* d_out, int out_size, void* d_ws, size_t ws_size,
                              hipStream_t stream)
{
    const float* X = (const float*)d_in[0];  // [256][1152][8]
    const float* W = (const float*)d_in[1];  // [10][1152][16][8]
    float* out = (float*)d_out;              // [256][10][16]

    _Float16* Xh = (_Float16*)d_ws;          // NX halfs (4.7 MB)
    _Float16* Wh = Xh + NX;                  // NW halfs (2.9 MB)
    float* P     = (float*)(Wh + NW);        // NIT*NS floats (23.6 MB)
    float* V0raw = P + (size_t)NIT * NS;     // NS floats
    float* VV1   = V0raw + NS;               // NS floats
    float* VV2   = VV1 + NS;                 // NS floats; total ~31.7 MB

    const int grid = NBT * NIT;              // 2304 blocks of 256 threads
    const int rgrid = NS / 256;              // 160 blocks

    prep_kernel<<<1024, 256, 0, stream>>>(X, W, Xh, Wh);
    pass_kernel<0><<<grid, 256, 0, stream>>>(Xh, Wh, nullptr, P);
    red_kernel<0><<<rgrid, 256, 0, stream>>>(P, V0raw, VV1, nullptr);
    pass_kernel<1><<<grid, 256, 0, stream>>>(Xh, Wh, VV1, P);
    red_kernel<1><<<rgrid, 256, 0, stream>>>(P, V0raw, VV2, nullptr);
    pass_kernel<2><<<grid, 256, 0, stream>>>(Xh, Wh, VV2, P);
    red_kernel<2><<<rgrid, 256, 0, stream>>>(P, V0raw, out, nullptr);
}

// Round 12
// 159.583 us; speedup vs baseline: 1.1346x; 1.1346x over previous
//
#include <hip/hip_runtime.h>

typedef _Float16 h2 __attribute__((ext_vector_type(2)));
typedef _Float16 h8 __attribute__((ext_vector_type(8)));

#define BB 256
#define II 1152
#define QQ 8
#define JJ 10
#define PP 16

#define BT 32            // b per block (512 threads = 32 b-groups x 16 p-lanes)
#define IT 8             // i per block
#define NBT (BB / BT)    // 8
#define NIT (II / IT)    // 144
#define XRH 72           // halfs per staged-x b-row (64 + 8 pad)
#define WTILE (IT * PP * QQ)     // 1024 halfs per j in the LDS W-tile

#define NW (JJ * II * PP * QQ)   // 1474560
#define NX (BB * II * QQ)        // 2359296
#define NS (BB * JJ * PP)        // 40960
#define LOG2E 1.4426950408889634f

// ---------------------------------------------------------------------------
// 16-lane row sum via DPP (VALU pipe only).
// ---------------------------------------------------------------------------
template <int CTRL>
__device__ __forceinline__ float dpp_add(float v) {
    int s = __builtin_bit_cast(int, v);
    int t = __builtin_amdgcn_update_dpp(0, s, CTRL, 0xF, 0xF, true);
    return v + __builtin_bit_cast(float, t);
}
__device__ __forceinline__ float row_sum16(float v) {
    v = dpp_add<0xB1>(v);   // xor1
    v = dpp_add<0x4E>(v);   // xor2
    v = dpp_add<0x124>(v);  // row_ror:4
    v = dpp_add<0x128>(v);  // row_ror:8
    return v;
}

// 8-element f16 dot with fp32 accumulate: 4 x v_dot2_f32_f16.
__device__ __forceinline__ float dot8(h8 w, h8 x) {
    h2 w0 = __builtin_shufflevector(w, w, 0, 1), w1 = __builtin_shufflevector(w, w, 2, 3);
    h2 w2 = __builtin_shufflevector(w, w, 4, 5), w3 = __builtin_shufflevector(w, w, 6, 7);
    h2 x0 = __builtin_shufflevector(x, x, 0, 1), x1 = __builtin_shufflevector(x, x, 2, 3);
    h2 x2 = __builtin_shufflevector(x, x, 4, 5), x3 = __builtin_shufflevector(x, x, 6, 7);
    float acc = __builtin_amdgcn_fdot2(w0, x0, 0.0f, false);
    acc = __builtin_amdgcn_fdot2(w1, x1, acc, false);
    acc = __builtin_amdgcn_fdot2(w2, x2, acc, false);
    acc = __builtin_amdgcn_fdot2(w3, x3, acc, false);
    return acc;
}

// ---------------------------------------------------------------------------
// prep: W,X fp32 -> f16; zero S0/S1/S2 (contiguous).
// ---------------------------------------------------------------------------
__global__ __launch_bounds__(256) void prep_kernel(
    const float* __restrict__ X, const float* __restrict__ W,
    _Float16* __restrict__ Xh, _Float16* __restrict__ Wh,
    float* __restrict__ S)   // 3*NS floats
{
    const int g = blockIdx.x * 256 + threadIdx.x;
    const int stride = gridDim.x * 256;
    typedef _Float16 h4 __attribute__((ext_vector_type(4)));
    for (int k = g; k < NW / 4; k += stride) {
        const float4 f = ((const float4*)W)[k];
        h4 o = { (_Float16)f.x, (_Float16)f.y, (_Float16)f.z, (_Float16)f.w };
        ((h4*)Wh)[k] = o;
    }
    for (int k = g; k < NX / 4; k += stride) {
        const float4 f = ((const float4*)X)[k];
        h4 o = { (_Float16)f.x, (_Float16)f.y, (_Float16)f.z, (_Float16)f.w };
        ((h4*)Xh)[k] = o;
    }
    const float4 z = {0.f, 0.f, 0.f, 0.f};
    for (int k = g; k < 3 * NS / 4; k += stride) ((float4*)S)[k] = z;
}

// ---------------------------------------------------------------------------
// Fused routing pass, LDS-fed. Block = 512 threads = 32 b-groups x 16 p-lanes
// (BT=32: 25 KB LDS, VGPR~64 -> 4 blocks/CU = 32 waves/CU, and halves the
// per-b share of W staging vs BT=16).
// Hot-loop W reads: single base (ws + p*8 halfs) + compile-time immediate
// offsets j*2048B + i*256B -> ds_read_b128 with no per-read address VALU.
// exp: __builtin_amdgcn_exp2f (native v_exp_f32; plain exp2f lowers to the
// multi-inst OCML precise path without fast-math — R11 post-mortem suspect).
// vv[j] = squash(Sprev)[p]*log2e inline via DPP; R==1,it==0 persists v0;
// R==2 adds v0 (cumulative logits without a logit tensor). R==0: c uniform.
// ---------------------------------------------------------------------------
template <int R>
__global__ __launch_bounds__(512, 4) void pass_kernel(
    const _Float16* __restrict__ Xh,  // [B][I][Q] f16
    const _Float16* __restrict__ Wh,  // [J][I][P][Q] f16
    const float* __restrict__ Sprev,  // [B][J][P] (R>0)
    float* __restrict__ V0,           // [B][J][P] v0 (R1 writes it==0, R2 reads)
    float* __restrict__ Sout)         // [B][J][P] pre-zeroed accumulator
{
    __shared__ _Float16 ws[JJ * WTILE];  // 20.5 KB
    __shared__ _Float16 xs[BT * XRH];    // 4.6 KB

    const int bt = blockIdx.x & (NBT - 1);
    const int it = blockIdx.x >> 3;
    const int b0 = bt * BT;
    const int i0 = it * IT;
    const int tid = threadIdx.x;

    // ---- stage W tile: 1280 h8 chunks over 512 threads (coalesced 16B/lane)
    {
        const size_t jstride = (size_t)II * PP * QQ;
        const _Float16* wsrc = Wh + (size_t)i0 * PP * QQ;
        for (int c = tid; c < JJ * (WTILE / 8); c += 512) {
            const int j = c >> 7;          // 128 h8 chunks per j
            const int r = c & 127;
            *(h8*)(ws + j * WTILE + r * 8) = *(const h8*)(wsrc + j * jstride + r * 8);
        }
        // ---- stage x tile: 256 h8 chunks (first 256 threads)
        if (tid < 256) {
            const int xb = tid >> 3;       // 8 h8 per b-row
            const int xr = tid & 7;
            *(h8*)(xs + xb * XRH + xr * 8) =
                *(const h8*)(Xh + ((size_t)(b0 + xb) * II + i0) * QQ + xr * 8);
        }
    }
    __syncthreads();

    const int b_l = tid >> 4;
    const int p   = tid & 15;
    const int b   = b0 + b_l;

    // inline squash of Sprev -> vv (pre-scaled by log2e)
    float vv[JJ];
    if (R > 0) {
#pragma unroll
        for (int j = 0; j < JJ; ++j) {
            const float sp = Sprev[((size_t)b * JJ + j) * PP + p];
            const float n2 = row_sum16(sp * sp);
            const float scale = n2 * __builtin_amdgcn_rcpf(1.0f + n2)
                                   * __builtin_amdgcn_rsqf(n2 + 1e-7f);
            float v = sp * scale;
            if (R == 1) {
                if (it == 0) V0[((size_t)b * JJ + j) * PP + p] = v;
            } else {
                v += V0[((size_t)b * JJ + j) * PP + p];
            }
            vv[j] = v * LOG2E;
        }
    }

    float sacc[JJ];
#pragma unroll
    for (int j = 0; j < JJ; ++j) sacc[j] = 0.0f;

    const _Float16* wb = ws + p * QQ;        // single LDS base; imm offsets below
    const _Float16* xb = xs + b_l * XRH;

#pragma unroll
    for (int i = 0; i < IT; ++i) {
        const h8 x8 = *(const h8*)(xb + i * QQ);

        float h[JJ];
#pragma unroll
        for (int j = 0; j < JJ; ++j)
            h[j] = dot8(*(const h8*)(wb + j * WTILE + i * PP * QQ), x8);

        if (R == 0) {
#pragma unroll
            for (int j = 0; j < JJ; ++j) sacc[j] += h[j];
        } else {
            float e[JJ];
#pragma unroll
            for (int j = 0; j < JJ; ++j) {
                const float bj = row_sum16(vv[j] * h[j]);
                e[j] = __builtin_amdgcn_exp2f(bj);    // native v_exp_f32
            }
            float s01 = e[0] + e[1], s23 = e[2] + e[3], s45 = e[4] + e[5],
                  s67 = e[6] + e[7], s89 = e[8] + e[9];
            float t0 = s01 + s23, t1 = s45 + s67;
            const float sum = (t0 + t1) + s89;
            const float inv = __builtin_amdgcn_rcpf(sum);
#pragma unroll
            for (int j = 0; j < JJ; ++j) sacc[j] += (e[j] * inv) * h[j];
        }
    }

#pragma unroll
    for (int j = 0; j < JJ; ++j)
        atomicAdd(&Sout[((size_t)b * JJ + j) * PP + p],
                  (R == 0) ? 0.1f * sacc[j] : sacc[j]);
}

// ---------------------------------------------------------------------------
// final output squash (fp32 precise)
// ---------------------------------------------------------------------------
__global__ __launch_bounds__(256) void squash_out_kernel(const float* __restrict__ S,
                                                         float* __restrict__ V)
{
    const int idx = blockIdx.x * blockDim.x + threadIdx.x;  // (b*J + j)
    if (idx >= BB * JJ) return;
    const float4* sp = (const float4*)(S + idx * PP);
    float4 a = sp[0], b4 = sp[1], c4 = sp[2], d4 = sp[3];
    float s2 = a.x * a.x + a.y * a.y + a.z * a.z + a.w * a.w +
               b4.x * b4.x + b4.y * b4.y + b4.z * b4.z + b4.w * b4.w +
               c4.x * c4.x + c4.y * c4.y + c4.z * c4.z + c4.w * c4.w +
               d4.x * d4.x + d4.y * d4.y + d4.z * d4.z + d4.w * d4.w;
    const float scale = s2 / (1.0f + s2) / sqrtf(s2 + 1e-7f);
    a.x *= scale; a.y *= scale; a.z *= scale; a.w *= scale;
    b4.x *= scale; b4.y *= scale; b4.z *= scale; b4.w *= scale;
    c4.x *= scale; c4.y *= scale; c4.z *= scale; c4.w *= scale;
    d4.x *= scale; d4.y *= scale; d4.z *= scale; d4.w *= scale;
    float4* vp = (float4*)(V + idx * PP);
    vp[0] = a; vp[1] = b4; vp[2] = c4; vp[3] = d4;
}

extern "C" void kernel_launch(void* const* d_in, const int* in_sizes, int n_in,
                              void* d_out, int out_size, void* d_ws, size_t ws_size,
                              hipStream_t stream)
{
    const float* X = (const float*)d_in[0];  // [256][1152][8]
    const float* W = (const float*)d_in[1];  // [10][1152][16][8]
    float* out = (float*)d_out;              // [256][10][16]

    _Float16* Xh = (_Float16*)d_ws;          // NX halfs
    _Float16* Wh = Xh + NX;                  // NW halfs
    float* S0 = (float*)(Wh + NW);           // NS floats
    float* S1 = S0 + NS;
    float* S2 = S1 + NS;
    float* v0 = S2 + NS;                     // NS floats; total ~8.3 MB

    const int grid = NBT * NIT;  // 1152 blocks of 512 threads

    prep_kernel<<<1024, 256, 0, stream>>>(X, W, Xh, Wh, S0);
    pass_kernel<0><<<grid, 512, 0, stream>>>(Xh, Wh, nullptr, nullptr, S0);
    pass_kernel<1><<<grid, 512, 0, stream>>>(Xh, Wh, S0, v0, S1);
    pass_kernel<2><<<grid, 512, 0, stream>>>(Xh, Wh, S1, v0, S2);
    squash_out_kernel<<<10, 256, 0, stream>>>(S2, out);
}

// Round 13
// 134.208 us; speedup vs baseline: 1.3491x; 1.1891x over previous
//
#include <hip/hip_runtime.h>

typedef _Float16 h2 __attribute__((ext_vector_type(2)));
typedef _Float16 h8 __attribute__((ext_vector_type(8)));
typedef float f4 __attribute__((ext_vector_type(4)));

#define BB 256
#define II 1152
#define QQ 8
#define JJ 10
#define PP 16

#define BT 16            // b per block for routing passes (256 thr = 16 bg x 16 p)
#define IT 8             // i per block
#define NBT (BB / BT)    // 16
#define NIT (II / IT)    // 144
#define XRH 72           // halfs per staged-x b-row (64 + 8 pad)
#define WTILE (IT * PP * QQ)     // 1024 halfs per j in the LDS W-tile

#define NW (JJ * II * PP * QQ)   // 1474560
#define NX (BB * II * QQ)        // 2359296
#define NS (BB * JJ * PP)        // 40960
#define LOG2E 1.4426950408889634f

// ---------------------------------------------------------------------------
// 16-lane row sum via DPP (VALU pipe only).
// ---------------------------------------------------------------------------
template <int CTRL>
__device__ __forceinline__ float dpp_add(float v) {
    int s = __builtin_bit_cast(int, v);
    int t = __builtin_amdgcn_update_dpp(0, s, CTRL, 0xF, 0xF, true);
    return v + __builtin_bit_cast(float, t);
}
__device__ __forceinline__ float row_sum16(float v) {
    v = dpp_add<0xB1>(v);   // xor1
    v = dpp_add<0x4E>(v);   // xor2
    v = dpp_add<0x124>(v);  // row_ror:4
    v = dpp_add<0x128>(v);  // row_ror:8
    return v;
}

// 8-element f16 dot with fp32 accumulate: 4 x v_dot2_f32_f16.
__device__ __forceinline__ float dot8(h8 w, h8 x) {
    h2 w0 = __builtin_shufflevector(w, w, 0, 1), w1 = __builtin_shufflevector(w, w, 2, 3);
    h2 w2 = __builtin_shufflevector(w, w, 4, 5), w3 = __builtin_shufflevector(w, w, 6, 7);
    h2 x0 = __builtin_shufflevector(x, x, 0, 1), x1 = __builtin_shufflevector(x, x, 2, 3);
    h2 x2 = __builtin_shufflevector(x, x, 4, 5), x3 = __builtin_shufflevector(x, x, 6, 7);
    float acc = __builtin_amdgcn_fdot2(w0, x0, 0.0f, false);
    acc = __builtin_amdgcn_fdot2(w1, x1, acc, false);
    acc = __builtin_amdgcn_fdot2(w2, x2, acc, false);
    acc = __builtin_amdgcn_fdot2(w3, x3, acc, false);
    return acc;
}

// ---------------------------------------------------------------------------
// prep: W,X fp32 -> f16; zero S0/S1/S2 (contiguous).
// ---------------------------------------------------------------------------
__global__ __launch_bounds__(256) void prep_kernel(
    const float* __restrict__ X, const float* __restrict__ W,
    _Float16* __restrict__ Xh, _Float16* __restrict__ Wh,
    float* __restrict__ S)   // 3*NS floats
{
    const int g = blockIdx.x * 256 + threadIdx.x;
    const int stride = gridDim.x * 256;
    typedef _Float16 h4 __attribute__((ext_vector_type(4)));
    for (int k = g; k < NW / 4; k += stride) {
        const float4 f = ((const float4*)W)[k];
        h4 o = { (_Float16)f.x, (_Float16)f.y, (_Float16)f.z, (_Float16)f.w };
        ((h4*)Wh)[k] = o;
    }
    for (int k = g; k < NX / 4; k += stride) {
        const float4 f = ((const float4*)X)[k];
        h4 o = { (_Float16)f.x, (_Float16)f.y, (_Float16)f.z, (_Float16)f.w };
        ((h4*)Xh)[k] = o;
    }
    const float4 z = {0.f, 0.f, 0.f, 0.f};
    for (int k = g; k < 3 * NS / 4; k += stride) ((float4*)S)[k] = z;
}

// ---------------------------------------------------------------------------
// s0 via MFMA: s0[b,j,p] = 0.1 * sum_{i,q} W[j,i,p,q] * x[b,i,q].
// Uniform-c pass 0 is a pure GEMM over K=(i,q)=9216 — no routing loop needed.
// mfma_f32_16x16x32_f16: M=b(16), N=p(16), K=32=(4i x 8q).
//   A-frag: lane(m=lane&15, quad=lane>>4) = x[b0+m, i+quad, 0:8]  (contiguous h8)
//   B-frag: lane(n=lane&15, quad)         = W[j, i+quad, n, 0:8]  (contiguous h8)
//   C/D:    col=lane&15 (p), row=quad*4+reg (b)    [m89-verified layout]
// 1280 waves = 16 b-tiles x 10 j x 8 K-chunks; 36 MFMAs each; atomic finish.
// ---------------------------------------------------------------------------
__global__ __launch_bounds__(256) void s0_mfma_kernel(
    const _Float16* __restrict__ Xh, const _Float16* __restrict__ Wh,
    float* __restrict__ S0)
{
    const int wid  = blockIdx.x * 4 + (threadIdx.x >> 6);  // 0..1279
    const int lane = threadIdx.x & 63;
    const int bt  = wid / 80;
    const int rem = wid % 80;
    const int j   = rem >> 3;
    const int kc  = rem & 7;
    const int b0  = bt * 16;
    const int m    = lane & 15;
    const int quad = lane >> 4;
    const int ib   = kc * 144;           // this wave's i-range [ib, ib+144)

    const _Float16* ax = Xh + ((size_t)(b0 + m) * II + ib + quad) * QQ;
    const _Float16* bw = Wh + (((size_t)j * II + ib + quad) * PP + m) * QQ;

    f4 acc = {0.f, 0.f, 0.f, 0.f};
    for (int t = 0; t < 36; ++t) {       // 36 * 4 i = 144
        const h8 a = *(const h8*)ax;
        const h8 b = *(const h8*)bw;
        acc = __builtin_amdgcn_mfma_f32_16x16x32_f16(a, b, acc, 0, 0, 0);
        ax += 4 * QQ;
        bw += (size_t)4 * PP * QQ;
    }
#pragma unroll
    for (int r = 0; r < 4; ++r) {
        const int row = quad * 4 + r;    // b index
        atomicAdd(&S0[((size_t)(b0 + row) * JJ + j) * PP + m], 0.1f * acc[r]);
    }
}

// ---------------------------------------------------------------------------
// Fused routing pass (R = 1 or 2), LDS-fed. Block = 256 thr = 16 bg x 16 p.
// (R10 config — best measured; R12's BT=32 was neutral.)
// vv[j] = squash(Sprev)[p]*log2e inline via DPP; R==1,it==0 persists v0;
// R==2 adds v0 (cumulative logits without a logit tensor).
// ---------------------------------------------------------------------------
template <int R>
__global__ __launch_bounds__(256, 4) void pass_kernel(
    const _Float16* __restrict__ Xh,  // [B][I][Q] f16
    const _Float16* __restrict__ Wh,  // [J][I][P][Q] f16
    const float* __restrict__ Sprev,  // [B][J][P]
    float* __restrict__ V0,           // [B][J][P] v0 (R1 writes it==0, R2 reads)
    float* __restrict__ Sout)         // [B][J][P] pre-zeroed accumulator
{
    __shared__ _Float16 ws[JJ * WTILE];  // 20 KB
    __shared__ _Float16 xs[BT * XRH];    // 2.25 KB

    const int bt = blockIdx.x & (NBT - 1);
    const int it = blockIdx.x >> 4;
    const int b0 = bt * BT;
    const int i0 = it * IT;
    const int tid = threadIdx.x;

    // ---- stage W tile: 1280 h8 chunks, 5 per thread (coalesced 16B/lane)
    {
        const size_t jstride = (size_t)II * PP * QQ;
        const _Float16* wsrc = Wh + (size_t)i0 * PP * QQ;
#pragma unroll
        for (int k = 0; k < 5; ++k) {
            const int c = tid + k * 256;   // 0..1279
            const int j = c >> 7;          // 128 h8 chunks per j
            const int r = c & 127;
            *(h8*)(ws + j * WTILE + r * 8) = *(const h8*)(wsrc + j * jstride + r * 8);
        }
        if (tid < 128) {
            const int xb = tid >> 3;
            const int xr = tid & 7;
            *(h8*)(xs + xb * XRH + xr * 8) =
                *(const h8*)(Xh + ((size_t)(b0 + xb) * II + i0) * QQ + xr * 8);
        }
    }
    __syncthreads();

    const int b_l = tid >> 4;
    const int p   = tid & 15;
    const int b   = b0 + b_l;

    // inline squash of Sprev -> vv (pre-scaled by log2e)
    float vv[JJ];
#pragma unroll
    for (int j = 0; j < JJ; ++j) {
        const float sp = Sprev[((size_t)b * JJ + j) * PP + p];
        const float n2 = row_sum16(sp * sp);
        const float scale = n2 * __builtin_amdgcn_rcpf(1.0f + n2)
                               * __builtin_amdgcn_rsqf(n2 + 1e-7f);
        float v = sp * scale;
        if (R == 1) {
            if (it == 0) V0[((size_t)b * JJ + j) * PP + p] = v;
        } else {
            v += V0[((size_t)b * JJ + j) * PP + p];
        }
        vv[j] = v * LOG2E;
    }

    float sacc[JJ];
#pragma unroll
    for (int j = 0; j < JJ; ++j) sacc[j] = 0.0f;

    const _Float16* wb = ws + p * QQ;    // single LDS base; imm offsets below
    const _Float16* xb = xs + b_l * XRH;

#pragma unroll
    for (int i = 0; i < IT; ++i) {
        const h8 x8 = *(const h8*)(xb + i * QQ);

        float h[JJ];
#pragma unroll
        for (int j = 0; j < JJ; ++j)
            h[j] = dot8(*(const h8*)(wb + j * WTILE + i * PP * QQ), x8);

        float e[JJ];
#pragma unroll
        for (int j = 0; j < JJ; ++j) {
            const float bj = row_sum16(vv[j] * h[j]);
            e[j] = __builtin_amdgcn_exp2f(bj);       // native v_exp_f32
        }
        float s01 = e[0] + e[1], s23 = e[2] + e[3], s45 = e[4] + e[5],
              s67 = e[6] + e[7], s89 = e[8] + e[9];
        float t0 = s01 + s23, t1 = s45 + s67;
        const float sum = (t0 + t1) + s89;
        const float inv = __builtin_amdgcn_rcpf(sum);
#pragma unroll
        for (int j = 0; j < JJ; ++j) sacc[j] += (e[j] * inv) * h[j];
    }

#pragma unroll
    for (int j = 0; j < JJ; ++j)
        atomicAdd(&Sout[((size_t)b * JJ + j) * PP + p], sacc[j]);
}

// ---------------------------------------------------------------------------
// final output squash (fp32 precise)
// ---------------------------------------------------------------------------
__global__ __launch_bounds__(256) void squash_out_kernel(const float* __restrict__ S,
                                                         float* __restrict__ V)
{
    const int idx = blockIdx.x * blockDim.x + threadIdx.x;  // (b*J + j)
    if (idx >= BB * JJ) return;
    const float4* sp = (const float4*)(S + idx * PP);
    float4 a = sp[0], b4 = sp[1], c4 = sp[2], d4 = sp[3];
    float s2 = a.x * a.x + a.y * a.y + a.z * a.z + a.w * a.w +
               b4.x * b4.x + b4.y * b4.y + b4.z * b4.z + b4.w * b4.w +
               c4.x * c4.x + c4.y * c4.y + c4.z * c4.z + c4.w * c4.w +
               d4.x * d4.x + d4.y * d4.y + d4.z * d4.z + d4.w * d4.w;
    const float scale = s2 / (1.0f + s2) / sqrtf(s2 + 1e-7f);
    a.x *= scale; a.y *= scale; a.z *= scale; a.w *= scale;
    b4.x *= scale; b4.y *= scale; b4.z *= scale; b4.w *= scale;
    c4.x *= scale; c4.y *= scale; c4.z *= scale; c4.w *= scale;
    d4.x *= scale; d4.y *= scale; d4.z *= scale; d4.w *= scale;
    float4* vp = (float4*)(V + idx * PP);
    vp[0] = a; vp[1] = b4; vp[2] = c4; vp[3] = d4;
}

extern "C" void kernel_launch(void* const* d_in, const int* in_sizes, int n_in,
                              void* d_out, int out_size, void* d_ws, size_t ws_size,
                              hipStream_t stream)
{
    const float* X = (const float*)d_in[0];  // [256][1152][8]
    const float* W = (const float*)d_in[1];  // [10][1152][16][8]
    float* out = (float*)d_out;              // [256][10][16]

    _Float16* Xh = (_Float16*)d_ws;          // NX halfs
    _Float16* Wh = Xh + NX;                  // NW halfs
    float* S0 = (float*)(Wh + NW);           // NS floats
    float* S1 = S0 + NS;
    float* S2 = S1 + NS;
    float* v0 = S2 + NS;                     // NS floats; total ~8.3 MB

    const int grid = NBT * NIT;  // 2304 blocks of 256 threads

    prep_kernel<<<1024, 256, 0, stream>>>(X, W, Xh, Wh, S0);
    s0_mfma_kernel<<<320, 256, 0, stream>>>(Xh, Wh, S0);           // pass 0 as GEMM
    pass_kernel<1><<<grid, 256, 0, stream>>>(Xh, Wh, S0, v0, S1);
    pass_kernel<2><<<grid, 256, 0, stream>>>(Xh, Wh, S1, v0, S2);
    squash_out_kernel<<<10, 256, 0, stream>>>(S2, out);
}